// Round 8
// baseline (705.948 us; speedup 1.0000x reference)
//
#include <hip/hip_runtime.h>

// ExtractSearchWindows: out[b,h,w,rr,tt] = (uint8)Q[b, h+off+ry+ty, w+off+rx+tx],
// Q = input padded by 6; stored as INT32 (harness reads uint8 ref via int32 path).
// R3-R7: five structures all 250-290us (2.6-2.8 TB/s) vs fill's 6.24 TB/s.
// Shared invariant: every wave's 1KB store span was 16/64B-misaligned vs 128B
// lines (pixel stride 9604B). Theory: partial-line writes trigger L2
// fetch-on-write-miss -> RMW doubles HBM traffic (6.24/2.2 = 2.8 TB/s observed).
// R8: PX=32 -> block range = 2401*128B exactly -> block base 128B-aligned; flat
// span decomposition (no group stride) -> EVERY wave dwordx4 store is a 1KB span
// on 128B alignment. Decode via LDS table + incremental (p,j), plain stores.

#define KT 7
#define K2 49
#define MAX_SR 3
#define B_ 2
#define H_ 192
#define W_ 192
#define PAD 6
#define PX 32               // 32*d dwords per block; d=2401 -> 2401*128B (aligned)
#define PCOLS (PX + 2*PAD)  // 44
#define PSTRIDE 45
#define PROWS 13
#define NTHREADS 256
// grid = (192/32)*192*2 = 2304 blocks

typedef int vint4 __attribute__((ext_vector_type(4)));

__global__ __launch_bounds__(NTHREADS) void esw_kernel(
    const float* __restrict__ in, int* __restrict__ out,
    int cv, int offset, int d /* cv*cv*49 */, int cvmagic /* 65536/cv + 1 */)
{
    __shared__ int patch[PROWS * PSTRIDE];      // 585 ints
    __shared__ unsigned short tbl[K2 * K2];     // up to 2401 entries

    const int tid = threadIdx.x;
    const int w0 = blockIdx.x * PX;
    const int h  = blockIdx.y;
    const int b  = blockIdx.z;

    // Stage patch: rows h-6..h+6, cols w0-6..w0+37, uint8 trunc applied.
    const float* inb = in + b * (H_ * W_);
    for (int i = tid; i < PROWS * PCOLS; i += NTHREADS) {
        int dy = i / PCOLS;            // const divisor
        int dx = i - dy * PCOLS;
        int y = h + dy - PAD;
        int x = w0 + dx - PAD;
        int v = 0;
        if ((unsigned)y < (unsigned)H_ && (unsigned)x < (unsigned)W_)
            v = (int)inb[y * W_ + x];  // trunc; vals in [0,255)
        patch[dy * PSTRIDE + dx] = v;
    }
    // Pixel-independent gather table: tbl[j] = (off+ry+ty)*PSTRIDE + (off+rx+tx).
    for (int j = tid; j < d; j += NTHREADS) {
        int rr = j / K2;               // const divisor 49
        int tt = j - rr * K2;
        int ry = (rr * cvmagic) >> 16; // rr / cv (rr < 49)
        int rx = rr - ry * cv;
        int ty = tt / KT;              // const divisor 7
        int tx = tt - ty * KT;
        tbl[j] = (unsigned short)((offset + ry + ty) * PSTRIDE + (offset + rx + tx));
    }
    __syncthreads();

    // Flat 1KB-aligned wave spans over the block's 32*d contiguous dwords.
    const int total = PX * d;
    long long p0 = (long long)(b * H_ + h) * W_ + w0;   // multiple of 32
    int* outp = out + p0 * (long long)d;  // byte offset = (p0/32)*2401*128 -> 128B-aligned

    int g = 4 * tid;
    int j = g, p = 0;
    while (j >= d) { j -= d; ++p; }    // normalize (handles small d)
    for (; g < total; g += 4 * NTHREADS) {
        if (j + 3 < d) {               // quad within one pixel's run
            vint4 v;
            v.x = patch[tbl[j]     + p];
            v.y = patch[tbl[j + 1] + p];
            v.z = patch[tbl[j + 2] + p];
            v.w = patch[tbl[j + 3] + p];
            *(vint4*)(outp + g) = v;   // 1KB wave span, 128B-aligned
        } else {                       // straddle (~1 lane per wrap)
            #pragma unroll
            for (int u = 0; u < 4; ++u) {
                int jj = j + u, pp = p;
                if (jj >= d) { jj -= d; ++pp; }
                outp[g + u] = patch[tbl[jj] + pp];
            }
        }
        j += 4 * NTHREADS;
        while (j >= d) { j -= d; ++p; }
    }
}

extern "C" void kernel_launch(void* const* d_in, const int* in_sizes, int n_in,
                              void* d_out, int out_size, void* d_ws, size_t ws_size,
                              hipStream_t stream) {
    const float* in = (const float*)d_in[0];
    int* out = (int*)d_out;

    // out_size = B*H*W * cv^2 * 49
    int cv2 = out_size / (B_ * H_ * W_ * K2);
    int cv = 1;
    while (cv * cv < cv2) ++cv;
    int offset = MAX_SR - (cv - 1) / 2;
    int d = cv2 * K2;
    int cvmagic = 65536 / cv + 1;

    dim3 grid(W_ / PX, H_, B_);
    esw_kernel<<<grid, NTHREADS, 0, stream>>>(in, out, cv, offset, d, cvmagic);
}